// Round 7
// baseline (107.895 us; speedup 1.0000x reference)
//
#include <hip/hip_runtime.h>
#include <hip/hip_bf16.h>

// Problem constants (fixed by the reference setup)
#define B_  16
#define C_  64
#define H_  64
#define W_  64
#define O_  64
#define EPS 1e-6f
#define SLOPE 0.01f

typedef __bf16  bf16x8 __attribute__((ext_vector_type(8)));
typedef float   f32x4  __attribute__((ext_vector_type(4)));

// ---- static LDS layout (bytes) ----
// x tile: [r(3)][w(64)][p(2)][c2(32)] bf16, row stride 144 B (16B aligned)
#define XT_OFF   0
#define XT_SZ    27648          // 3 * 64 * 144
#define PMIN_OFF 27648          // float [p(2)][r(3)][w(64)] = 1536 B
#define PMAX_OFF 29184          // 1536 B
#define SINV_OFF 30720          // float [p(2)][w(64)] = 512 B
#define SEPS_OFF 31232          // 512 B
#define SMEM_SZ  31744          // 31 KB -> 5 blocks/CU by LDS

__device__ __forceinline__ unsigned short f2bf(float f) {
  unsigned u = __float_as_uint(f);         // fp32 -> bf16 RNE
  u += 0x7fffu + ((u >> 16) & 1u);
  return (unsigned short)(u >> 16);
}

__device__ __forceinline__ int clampi(int v, int lo, int hi) {
  return v < lo ? lo : (v > hi ? hi : v);
}

// Single fused kernel. Block = (b, h): one output row, all 64 o, all 64 w.
// 4 waves; wave wv owns o-slice o0 = wv*16. Weights gathered per-wave from
// the ORIGINAL W[o][c][j][i] fp32 layout (L2-hot, 147 KB reread per block),
// so no pre-transform kernel and no d_ws use.
__launch_bounds__(256, 3)
__global__ void conv_fused_kernel(const float* __restrict__ x,
                                  const float* __restrict__ Wsrc,
                                  const float* __restrict__ bias,
                                  float* __restrict__ out) {
  __shared__ char smem[SMEM_SZ];
  const int tid  = threadIdx.x;
  const int lane = tid & 63;
  const int wv   = tid >> 6;
  const int b    = blockIdx.x >> 6;
  const int h    = blockIdx.x & 63;
  const int l15  = lane & 15;
  const int q    = lane >> 4;
  const int o0   = wv * 16;

  // ---- stage x rows h-1..h+1 (replicate-clamped) into [r][w][p][c2] bf16,
  //      folding per-(r,p,w) fp32 min/max into the same pass. Waves 0..2 only
  //      (192 threads cover 3 rows x 64 w; each thread does all 64 channels).
  if (wv < 3) {
    const int w = tid & 63;
    const int r = wv;
    const int hr = clampi(h - 1 + r, 0, H_ - 1);
    const float* xb = x + ((size_t)b * C_ * H_ * W_) + hr * W_ + w;
    float mn[2] = {3.4e38f, 3.4e38f}, mx[2] = {-3.4e38f, -3.4e38f};
    #pragma unroll
    for (int pm = 0; pm < 8; ++pm) {
      const int p = pm >> 2, m = pm & 3;
      unsigned d[4];
      #pragma unroll
      for (int e = 0; e < 4; ++e) {
        const int c2a = m * 8 + 2 * e;
        const float f0 = xb[(2 * c2a + p) * (H_ * W_)];
        const float f1 = xb[(2 * (c2a + 1) + p) * (H_ * W_)];
        mn[p] = fminf(mn[p], fminf(f0, f1));
        mx[p] = fmaxf(mx[p], fmaxf(f0, f1));
        d[e] = (unsigned)f2bf(f0) | ((unsigned)f2bf(f1) << 16);
      }
      *(uint4*)(smem + XT_OFF + (r * 64 + w) * 144 + p * 64 + m * 16) =
          make_uint4(d[0], d[1], d[2], d[3]);
    }
    ((float*)(smem + PMIN_OFF))[(0 * 3 + r) * 64 + w] = mn[0];
    ((float*)(smem + PMIN_OFF))[(1 * 3 + r) * 64 + w] = mn[1];
    ((float*)(smem + PMAX_OFF))[(0 * 3 + r) * 64 + w] = mx[0];
    ((float*)(smem + PMAX_OFF))[(1 * 3 + r) * 64 + w] = mx[1];
  }
  __syncthreads();

  // ---- s-pass: 3x3 window reduce -> (s+eps), 1/(s+eps) per (p, w) ----
  if (tid < 128) {
    const int p = tid >> 6, ww = tid & 63;
    const float* pmin = (const float*)(smem + PMIN_OFF);
    const float* pmax = (const float*)(smem + PMAX_OFF);
    float mn = 3.4e38f, mx = -3.4e38f;
    #pragma unroll
    for (int r = 0; r < 3; ++r) {
      #pragma unroll
      for (int dw = -1; dw <= 1; ++dw) {
        const int wc = clampi(ww + dw, 0, W_ - 1);
        mn = fminf(mn, pmin[(p * 3 + r) * 64 + wc]);
        mx = fmaxf(mx, pmax[(p * 3 + r) * 64 + wc]);
      }
    }
    const float sv = (mx - mn) + EPS;
    ((float*)(smem + SEPS_OFF))[p * 64 + ww] = sv;
    ((float*)(smem + SINV_OFF))[p * 64 + ww] = 1.0f / sv;
  }
  __syncthreads();

  // ---- MFMA: one parity at a time; per-i weight gather keeps VGPRs low.
  //      A[m=o][k=c2] fragment: m = l15 (o = o0+l15), k = q*8+e (c = 2k+p),
  //      element e of af[j] = W[(o0+l15)*576 + (2*(q*8+e)+p)*9 + j*3 + i].
  const float* sinv = (const float*)(smem + SINV_OFF);
  const f32x4 zero = {0.0f, 0.0f, 0.0f, 0.0f};
  f32x4 oacc[4];
  #pragma unroll
  for (int nt = 0; nt < 4; ++nt) oacc[nt] = zero;

  const float* wbase = Wsrc + (o0 + l15) * 576;

  #pragma unroll 1
  for (int p = 0; p < 2; ++p) {
    f32x4 acc[4];
    #pragma unroll
    for (int nt = 0; nt < 4; ++nt) acc[nt] = zero;

    #pragma unroll
    for (int i = 0; i < 3; ++i) {
      // gather the 3 taps (j=0..2) of kernel-row i for this parity
      bf16x8 af3[3];
      #pragma unroll
      for (int j = 0; j < 3; ++j) {
        union { uint4 u; bf16x8 v; } cvt;
        unsigned pk[4];
        #pragma unroll
        for (int eo = 0; eo < 4; ++eo) {
          const float f0 = wbase[(2 * (q * 8 + 2 * eo) + p) * 9 + j * 3 + i];
          const float f1 = wbase[(2 * (q * 8 + 2 * eo + 1) + p) * 9 + j * 3 + i];
          pk[eo] = (unsigned)f2bf(f0) | ((unsigned)f2bf(f1) << 16);
        }
        cvt.u = make_uint4(pk[0], pk[1], pk[2], pk[3]);
        af3[j] = cvt.v;
      }
      const char* row = smem + XT_OFF + (i * 64) * 144 + p * 64 + q * 16;
      #pragma unroll
      for (int nt = 0; nt < 4; ++nt) {
        bf16x8 bfr[3];                // B[k=c2][n=w], n=l15, k=q*8+e
        #pragma unroll
        for (int j = 0; j < 3; ++j) {
          const int wc = clampi(nt * 16 + l15 + j - 1, 0, W_ - 1);
          bfr[j] = *(const bf16x8*)(row + wc * 144);
        }
        #pragma unroll
        for (int j = 0; j < 3; ++j)
          acc[nt] = __builtin_amdgcn_mfma_f32_16x16x32_bf16(
              af3[j], bfr[j], acc[nt], 0, 0, 0);
      }
    }

    // fold this parity: oacc += acc * 1/(s_p + eps)
    #pragma unroll
    for (int nt = 0; nt < 4; ++nt) {
      const float sv = sinv[p * 64 + nt * 16 + l15];
      #pragma unroll
      for (int reg = 0; reg < 4; ++reg)
        oacc[nt][reg] += acc[nt][reg] * sv;
    }
  }

  // ---- epilogue: bias, leaky-relu, re-scale by (s_{o%2}+eps), store fp32 ----
  // D layout: col(w) = l15, row(o-within-16) = q*4 + reg
  const float* seps = (const float*)(smem + SEPS_OFF);
  float bv[4];
  #pragma unroll
  for (int reg = 0; reg < 4; ++reg) bv[reg] = bias[o0 + q * 4 + reg];

  #pragma unroll
  for (int nt = 0; nt < 4; ++nt) {
    const int wpx = nt * 16 + l15;
    const float se0 = seps[0 * 64 + wpx];
    const float se1 = seps[1 * 64 + wpx];
    #pragma unroll
    for (int reg = 0; reg < 4; ++reg) {
      const int o = o0 + q * 4 + reg;
      float v = oacc[nt][reg] + bv[reg];
      v = v >= 0.0f ? v : SLOPE * v;
      v *= (reg & 1) ? se1 : se0;            // o&1 == reg&1 (q*4 even)
      out[(((size_t)b * O_ + o) * H_ + h) * W_ + wpx] = v;
    }
  }
}

extern "C" void kernel_launch(void* const* d_in, const int* in_sizes, int n_in,
                              void* d_out, int out_size, void* d_ws, size_t ws_size,
                              hipStream_t stream) {
  const float* x    = (const float*)d_in[0];
  const float* Wsrc = (const float*)d_in[1];
  const float* bias = (const float*)d_in[2];
  float* out = (float*)d_out;
  (void)d_ws; (void)ws_size;

  conv_fused_kernel<<<1024, 256, 0, stream>>>(x, Wsrc, bias, out);
}

// Round 8
// 100.085 us; speedup vs baseline: 1.0780x; 1.0780x over previous
//
#include <hip/hip_runtime.h>
#include <hip/hip_bf16.h>

// Problem constants (fixed by the reference setup)
#define B_  16
#define C_  64
#define H_  64
#define W_  64
#define O_  64
#define EPS 1e-6f
#define SLOPE 0.01f

typedef __bf16  bf16x8 __attribute__((ext_vector_type(8)));
typedef float   f32x4  __attribute__((ext_vector_type(4)));

// ---- d_ws layout (bytes) ----
// Wt  @ 0       : bf16 [tap(9)][p(2)][o(64)][c2(32)]          =    73,728 B
// xt  @ 131072  : bf16 [b(16)][h(64)][p(2)][w(64)][c2(32)]    = 8,388,608 B
// pmm @ 8519680 : fp32 [map(2)][b(16)][p(2)][h(64)][w(64)]    = 1,048,576 B
#define XT_WS_OFF  131072
#define PMM_WS_OFF 8519680

#define RAWC 65   // padded LDS leading dim (65 deg 1 mod 32 -> conflict-free)

__device__ __forceinline__ unsigned short f2bf(float f) {
  unsigned u = __float_as_uint(f);         // fp32 -> bf16 RNE
  u += 0x7fffu + ((u >> 16) & 1u);
  return (unsigned short)(u >> 16);
}

__device__ __forceinline__ int clampi(int v, int lo, int hi) {
  return v < lo ? lo : (v > hi ? hi : v);
}

// prep: blocks 0..1023 = (b, h): stage 64ch x 64w fp32 via 4 independent
// float4 loads/thread -> padded LDS transpose -> pack bf16 xt[b][h][p][w][c2]
// + per-pixel channel min/max -> pmm. Blocks 1024..1032: weight transform
// W[o][c][j][i] fp32 -> bf16 Wt[((tap*2+p)*64+o)*32+c2], tap = i*3+j
// (einsum 'bcijhw,ocji': tap (i,j) uses W[o][c][j][i]).
__global__ __launch_bounds__(256)
void prep_kernel(const float* __restrict__ x,
                 const float* __restrict__ Wsrc,
                 unsigned short* __restrict__ Wt,
                 char* __restrict__ xt,
                 float* __restrict__ pmm) {
  __shared__ float raw[64 * RAWC];      // [w][c + pad]
  __shared__ float red[2][4][64];       // [map][half(c2s*2+p)][w]

  if (blockIdx.x >= 1024) {             // ---- weight-transform blocks ----
    const int idx0 = (int)(blockIdx.x - 1024) * 4096 + threadIdx.x * 16;
    const float4* src = (const float4*)(Wsrc + idx0);
    float f[16];
    #pragma unroll
    for (int k = 0; k < 4; ++k) {
      const float4 v = src[k];
      f[k * 4 + 0] = v.x; f[k * 4 + 1] = v.y;
      f[k * 4 + 2] = v.z; f[k * 4 + 3] = v.w;
    }
    #pragma unroll
    for (int e = 0; e < 16; ++e) {
      const int idx = idx0 + e;
      const int i = idx % 3;
      const int j = (idx / 3) % 3;
      const int c = (idx / 9) & 63;
      const int o = idx / 576;
      const int tap = i * 3 + j;
      Wt[((tap * 2 + (c & 1)) * 64 + o) * 32 + (c >> 1)] = f2bf(f[e]);
    }
    return;
  }

  const int b    = blockIdx.x >> 6;
  const int h    = blockIdx.x & 63;
  const int lane = threadIdx.x & 63;
  const int wv   = threadIdx.x >> 6;

  // ---- stage: 4 independent float4 loads/thread (coalesced 256 B segs) ----
  {
    const int w4 = (lane & 15) * 4;
    const int cb = wv * 16 + (lane >> 4);
    #pragma unroll
    for (int k = 0; k < 4; ++k) {
      const int c = cb + k * 4;
      const float4 v = *(const float4*)(x + (((size_t)b * C_ + c) * H_ + h) * W_ + w4);
      raw[(w4 + 0) * RAWC + c] = v.x;
      raw[(w4 + 1) * RAWC + c] = v.y;
      raw[(w4 + 2) * RAWC + c] = v.z;
      raw[(w4 + 3) * RAWC + c] = v.w;
    }
  }
  __syncthreads();

  // ---- transform: thread (w, p, c2s) packs 16 c2 + partial min/max ----
  {
    const int w    = threadIdx.x & 63;
    const int half = threadIdx.x >> 6;      // = c2s*2 + p
    const int p    = half & 1;
    const int c2s  = half >> 1;
    float mn = 3.4e38f, mx = -3.4e38f;
    unsigned pk[8];
    #pragma unroll
    for (int u = 0; u < 16; ++u) {
      const int c2 = c2s * 16 + u;
      const float f = raw[w * RAWC + 2 * c2 + p];
      mn = fminf(mn, f);
      mx = fmaxf(mx, f);
      const unsigned hb = f2bf(f);
      if (u & 1) pk[u >> 1] |= (hb << 16);
      else       pk[u >> 1]  = hb;
    }
    char* dst = xt + ((size_t)(((b * 64 + h) * 2 + p) * 64 + w)) * 64 + c2s * 32;
    *(uint4*)(dst)      = make_uint4(pk[0], pk[1], pk[2], pk[3]);
    *(uint4*)(dst + 16) = make_uint4(pk[4], pk[5], pk[6], pk[7]);
    red[0][half][w] = mn;
    red[1][half][w] = mx;
  }
  __syncthreads();

  // ---- combine the two c2s halves -> pmm ----
  {
    const int map = threadIdx.x >> 7;
    const int p   = (threadIdx.x >> 6) & 1;
    const int w   = threadIdx.x & 63;
    const float a = red[map][p][w], c = red[map][2 + p][w];
    const float v = map ? fmaxf(a, c) : fminf(a, c);
    pmm[((size_t)(map * 16 + b) * 2 + p) * 4096 + h * 64 + w] = v;
  }
}

// gemm: zero LDS, zero barriers, whole grid resident. Block = (b, h); wave wv
// owns o-slice o0 = wv*16 for the full 64-w row. All loads coalesced dwordx4.
__global__ __launch_bounds__(256, 4)
void gemm_kernel(const char* __restrict__ xt,
                 const unsigned short* __restrict__ Wt,
                 const float* __restrict__ pmm,
                 const float* __restrict__ bias,
                 float* __restrict__ out) {
  const int b    = blockIdx.x >> 6;
  const int h    = blockIdx.x & 63;
  const int wv   = threadIdx.x >> 6;
  const int lane = threadIdx.x & 63;
  const int l15  = lane & 15;
  const int q    = lane >> 4;
  const int o0   = wv * 16;

  // ---- per-lane (w = lane) scale factors: separable 3x3 window of pmm ----
  float si[2], se[2];
  #pragma unroll
  for (int p = 0; p < 2; ++p) {
    float mn = 3.4e38f, mx = -3.4e38f;
    #pragma unroll
    for (int r = 0; r < 3; ++r) {
      const int hr = clampi(h - 1 + r, 0, H_ - 1);
      mn = fminf(mn, pmm[((size_t)(0 * 16 + b) * 2 + p) * 4096 + hr * 64 + lane]);
      mx = fmaxf(mx, pmm[((size_t)(1 * 16 + b) * 2 + p) * 4096 + hr * 64 + lane]);
    }
    const float mnl = __shfl(mn, clampi(lane - 1, 0, 63));
    const float mnr = __shfl(mn, clampi(lane + 1, 0, 63));
    const float mxl = __shfl(mx, clampi(lane - 1, 0, 63));
    const float mxr = __shfl(mx, clampi(lane + 1, 0, 63));
    mn = fminf(mn, fminf(mnl, mnr));
    mx = fmaxf(mx, fmaxf(mxl, mxr));
    const float sv = (mx - mn) + EPS;
    se[p] = sv;
    si[p] = 1.0f / sv;
  }

  // ---- MFMA: one parity at a time; fold acc * 1/(s_p+eps) into oacc ----
  const f32x4 zero = {0.0f, 0.0f, 0.0f, 0.0f};
  f32x4 oacc[4];
  #pragma unroll
  for (int nt = 0; nt < 4; ++nt) oacc[nt] = zero;

  #pragma unroll 1
  for (int p = 0; p < 2; ++p) {
    bf16x8 af[9];                     // A[m=o][k=c2], m=l15, k=q*8+e
    #pragma unroll
    for (int t9 = 0; t9 < 9; ++t9)
      af[t9] = *(const bf16x8*)(Wt + ((t9 * 2 + p) * 64 + o0 + l15) * 32 + q * 8);

    f32x4 acc[4];
    #pragma unroll
    for (int nt = 0; nt < 4; ++nt) acc[nt] = zero;

    #pragma unroll
    for (int i = 0; i < 3; ++i) {
      const int hr = clampi(h - 1 + i, 0, H_ - 1);
      const char* row = xt + ((size_t)((b * 64 + hr) * 2 + p)) * 4096;
      #pragma unroll
      for (int nt = 0; nt < 4; ++nt) {
        bf16x8 bfr[3];                // B[k=c2][n=w], n=l15, k=q*8+e
        #pragma unroll
        for (int j = 0; j < 3; ++j) {
          const int wc = clampi(nt * 16 + l15 + j - 1, 0, W_ - 1);
          bfr[j] = *(const bf16x8*)(row + wc * 64 + q * 16);
        }
        #pragma unroll
        for (int j = 0; j < 3; ++j)
          acc[nt] = __builtin_amdgcn_mfma_f32_16x16x32_bf16(
              af[i * 3 + j], bfr[j], acc[nt], 0, 0, 0);
      }
    }

    #pragma unroll
    for (int nt = 0; nt < 4; ++nt) {
      const float sv = __shfl(si[p], nt * 16 + l15);
      #pragma unroll
      for (int reg = 0; reg < 4; ++reg)
        oacc[nt][reg] += acc[nt][reg] * sv;
    }
  }

  // ---- epilogue: bias, leaky-relu, re-scale by (s_{o%2}+eps), store ----
  // D layout: col(w) = l15, row(o-within-16) = q*4 + reg
  float bv[4];
  #pragma unroll
  for (int reg = 0; reg < 4; ++reg) bv[reg] = bias[o0 + q * 4 + reg];

  #pragma unroll
  for (int nt = 0; nt < 4; ++nt) {
    const int wpx = nt * 16 + l15;
    const float se0 = __shfl(se[0], wpx);
    const float se1 = __shfl(se[1], wpx);
    #pragma unroll
    for (int reg = 0; reg < 4; ++reg) {
      const int o = o0 + q * 4 + reg;
      float v = oacc[nt][reg] + bv[reg];
      v = v >= 0.0f ? v : SLOPE * v;
      v *= (reg & 1) ? se1 : se0;            // o&1 == reg&1 (q*4 even)
      out[(((size_t)b * O_ + o) * H_ + h) * W_ + wpx] = v;
    }
  }
}

extern "C" void kernel_launch(void* const* d_in, const int* in_sizes, int n_in,
                              void* d_out, int out_size, void* d_ws, size_t ws_size,
                              hipStream_t stream) {
  const float* x    = (const float*)d_in[0];
  const float* Wsrc = (const float*)d_in[1];
  const float* bias = (const float*)d_in[2];
  float* out = (float*)d_out;

  unsigned short* Wt = (unsigned short*)d_ws;
  char*  xt  = (char*)d_ws + XT_WS_OFF;
  float* pmm = (float*)((char*)d_ws + PMM_WS_OFF);

  prep_kernel<<<1024 + 9, 256, 0, stream>>>(x, Wsrc, Wt, xt, pmm);
  gemm_kernel<<<1024, 256, 0, stream>>>(xt, Wt, pmm, bias, out);
}